// Round 1
// baseline (1005.876 us; speedup 1.0000x reference)
//
#include <hip/hip_runtime.h>

// RelScaledDotProductAttention:
//   attn = softmax(q @ k^T / 8)           -> output 1 [NB, LQ, LK]
//   out  = einsum("nqk,nqkd->nqd", attn, rel_pos_v)  -> output 0 [NB, LQ, DV]
// v (d_in[2]) and rel_pos (d_in[3]) are unused by the reference outputs.
// Memory-bound: rel_pos_v is 604 MB fp32, streamed once.

#define NB 16
#define LQ 384
#define LK 384
#define DK 64
#define DV 64
#define INV_T 0.125f   // 1 / TEMPERATURE(=8)

__global__ __launch_bounds__(256) void rel_attn_fused_kernel(
    const float* __restrict__ qp,
    const float* __restrict__ kp,
    const float* __restrict__ rpv,
    float* __restrict__ out,      // [NB*LQ*DV]
    float* __restrict__ attn_out) // [NB*LQ*LK]
{
    const int bid = blockIdx.x;        // n*LQ + q_row
    const int tid = threadIdx.x;       // 0..255
    const int n   = bid / LQ;

    __shared__ float spart[LK * 4];    // per-quarter partial dots (6 KB)
    __shared__ float s[LK];            // scores -> probs (1.5 KB)
    __shared__ float red[256];         // block reductions (1 KB)
    __shared__ float4 oacc[4][16];     // cross-wave output partials (1 KB)

    // ---------------- phase 1: scores s[k] = (q_row . k_row) / 8 ----------------
    // thread owns quarter `part` (16 dims) of q; handles 6 k-rows (kk = j*64 + tid/4)
    {
        const int part  = tid & 3;
        const int krow0 = tid >> 2;
        const float4* q4 = (const float4*)qp + (size_t)bid * 16 + part * 4;
        const float4 qv0 = q4[0], qv1 = q4[1], qv2 = q4[2], qv3 = q4[3];
        const float4* k4 = (const float4*)kp + (size_t)n * (LK * 16) + part * 4;
        #pragma unroll
        for (int j = 0; j < 6; ++j) {
            const int kk = j * 64 + krow0;
            const float4* kr = k4 + kk * 16;
            const float4 a = kr[0], b = kr[1], c = kr[2], d = kr[3];
            float dot;
            dot  = qv0.x * a.x + qv0.y * a.y + qv0.z * a.z + qv0.w * a.w;
            dot += qv1.x * b.x + qv1.y * b.y + qv1.z * b.z + qv1.w * b.w;
            dot += qv2.x * c.x + qv2.y * c.y + qv2.z * c.z + qv2.w * c.w;
            dot += qv3.x * d.x + qv3.y * d.y + qv3.z * d.z + qv3.w * d.w;
            spart[kk * 4 + part] = dot;   // contiguous across the wave
        }
    }
    __syncthreads();

    // ---------------- phase 2: softmax over k (deterministic LDS trees) ----------------
    float lmax = -1e30f;
    for (int kk = tid; kk < LK; kk += 256) {
        float v = (spart[4*kk] + spart[4*kk+1] + spart[4*kk+2] + spart[4*kk+3]) * INV_T;
        s[kk] = v;
        lmax = fmaxf(lmax, v);
    }
    red[tid] = lmax;
    __syncthreads();
    #pragma unroll
    for (int off = 128; off > 0; off >>= 1) {
        if (tid < off) red[tid] = fmaxf(red[tid], red[tid + off]);
        __syncthreads();
    }
    const float m = red[0];
    __syncthreads();                    // everyone has read red[0] before reuse

    float lsum = 0.f;
    for (int kk = tid; kk < LK; kk += 256) {
        float e = __expf(s[kk] - m);
        s[kk] = e;                       // each kk owned by exactly one thread
        lsum += e;
    }
    red[tid] = lsum;
    __syncthreads();
    #pragma unroll
    for (int off = 128; off > 0; off >>= 1) {
        if (tid < off) red[tid] += red[tid + off];
        __syncthreads();
    }
    const float inv = 1.0f / red[0];

    for (int kk = tid; kk < LK; kk += 256) {
        float p = s[kk] * inv;
        s[kk] = p;
        attn_out[(size_t)bid * LK + kk] = p;   // output 1, coalesced
    }
    __syncthreads();

    // ---------------- phase 3: out_row[d] = sum_k p[k] * rpv[bid,k,d] ----------------
    // float4 stream: thread handles (kg = tid/16) k-group, (d4 = tid%16) dim-quad.
    const int d4 = tid & 15;
    const int kg = tid >> 4;
    const float4* r4 = (const float4*)rpv + (size_t)bid * (LK * 16) + kg * 16 + d4;
    float4 acc = make_float4(0.f, 0.f, 0.f, 0.f);
    #pragma unroll 8
    for (int it = 0; it < 24; ++it) {
        const float p = s[kg + it * 16];        // LDS broadcast within 16-lane group
        const float4 r = r4[(size_t)it * 256];  // fully coalesced 16B/lane
        acc.x += p * r.x;
        acc.y += p * r.y;
        acc.z += p * r.z;
        acc.w += p * r.w;
    }

    // reduce across the 4 kg-groups inside each wave (lanes +32, +16)
    acc.x += __shfl_down(acc.x, 32); acc.y += __shfl_down(acc.y, 32);
    acc.z += __shfl_down(acc.z, 32); acc.w += __shfl_down(acc.w, 32);
    acc.x += __shfl_down(acc.x, 16); acc.y += __shfl_down(acc.y, 16);
    acc.z += __shfl_down(acc.z, 16); acc.w += __shfl_down(acc.w, 16);

    const int wave = tid >> 6;
    const int lane = tid & 63;
    if (lane < 16) oacc[wave][lane] = acc;
    __syncthreads();

    if (tid < 16) {
        const float4 a0 = oacc[0][tid], a1 = oacc[1][tid];
        const float4 a2 = oacc[2][tid], a3 = oacc[3][tid];
        float4 r;
        r.x = (a0.x + a1.x) + (a2.x + a3.x);
        r.y = (a0.y + a1.y) + (a2.y + a3.y);
        r.z = (a0.z + a1.z) + (a2.z + a3.z);
        r.w = (a0.w + a1.w) + (a2.w + a3.w);
        ((float4*)(out + (size_t)bid * DV))[tid] = r;   // output 0, coalesced
    }
}

extern "C" void kernel_launch(void* const* d_in, const int* in_sizes, int n_in,
                              void* d_out, int out_size, void* d_ws, size_t ws_size,
                              hipStream_t stream) {
    const float* q   = (const float*)d_in[0];
    const float* k   = (const float*)d_in[1];
    // d_in[2] = v       : unused by the reference outputs
    // d_in[3] = rel_pos : unused by the reference outputs
    const float* rpv = (const float*)d_in[4];

    float* out  = (float*)d_out;                       // [NB*LQ*DV]
    float* attn = out + (size_t)NB * LQ * DV;          // [NB*LQ*LK]

    rel_attn_fused_kernel<<<NB * LQ, 256, 0, stream>>>(q, k, rpv, out, attn);
}